// Round 2
// baseline (167.235 us; speedup 1.0000x reference)
//
#include <hip/hip_runtime.h>
#include <stdint.h>

typedef __attribute__((ext_vector_type(8))) __bf16 bf16x8;
typedef __attribute__((ext_vector_type(4))) float f32x4;

// Selected upper-tri circular-adjacency pairs (r,c), row-major triu order. K=64.
__device__ const unsigned char dR[64] = {
  0,0,0,0,0,0,0,
  1,1,1,1,1,1,
  2,2,2,2,2,
  3,3,3,3,
  4,4,4,4,
  5,5,5,5,
  6,6,6,6,
  7,7,7,7,
  8,8,8,8,
  9,9,9,9,
  10,10,10,10,
  11,11,11,11,
  12,12,12,12,
  13,13,13,
  14,14,
  15};
__device__ const unsigned char dC[64] = {
  0,1,2,3,13,14,15,
  1,2,3,4,14,15,
  2,3,4,5,15,
  3,4,5,6,
  4,5,6,7,
  5,6,7,8,
  6,7,8,9,
  7,8,9,10,
  8,9,10,11,
  9,10,11,12,
  10,11,12,13,
  11,12,13,14,
  12,13,14,15,
  13,14,15,
  14,15,
  15};

__device__ __forceinline__ unsigned short f2bf(float x){
  unsigned u = __builtin_bit_cast(unsigned, x);
  return (unsigned short)((u + 0x7FFFu + ((u >> 16) & 1u)) >> 16);
}

// fp32 -> bf16 weight conversion into workspace (2.62 MB total)
__global__ void conv_w_kernel(const float* __restrict__ w1, const float* __restrict__ w2,
                              unsigned short* __restrict__ o1, unsigned short* __restrict__ o2){
  int i = blockIdx.x * 256 + threadIdx.x;
  if (i < 262144){                       // W1: 512*2048 = 262144 float4 groups
    float4 v = ((const float4*)w1)[i];
    ushort4 pk; pk.x=f2bf(v.x); pk.y=f2bf(v.y); pk.z=f2bf(v.z); pk.w=f2bf(v.w);
    ((ushort4*)o1)[i] = pk;
  } else {
    int j = i - 262144;
    if (j < 65536){                      // W2: 512*512
      float4 v = ((const float4*)w2)[j];
      ushort4 pk; pk.x=f2bf(v.x); pk.y=f2bf(v.y); pk.z=f2bf(v.z); pk.w=f2bf(v.w);
      ((ushort4*)o2)[j] = pk;
    }
  }
}

// LDS map: [0,49152)      A1 [o*16+t][512] bf16, XOR-swizzled (phase 2, written in epilogue 1)
//          [49152,55296)  gather dbuf: 2 x 3072B tiles [o][kb4][t16][e8] bf16
#define LDS_G 49152

__global__ __launch_bounds__(512, 4)
void fused_kernel(const float* __restrict__ x,
                  const float* __restrict__ b1v,
                  const float* __restrict__ b2v,
                  const unsigned short* __restrict__ w1b,
                  const unsigned short* __restrict__ w2b,
                  float* __restrict__ out)
{
  __shared__ char lds[55296];
  const int bid = blockIdx.x;
  const int wg  = ((bid & 7) << 6) | (bid >> 3);   // bijective XCD swizzle (512 % 8 == 0)
  const int b   = wg >> 4;
  const int t0  = (wg & 15) << 4;

  const int tid  = threadIdx.x;
  const int w    = tid >> 6;
  const int lane = tid & 63;
  const int q    = lane >> 4;
  const int lr   = lane & 15;
  const int klA  = tid >> 4;
  const int tA   = tid & 15;

  // gather source offsets (element offset inside the [16][16][256] (i,j,t) slab)
  int poff[2][3];
#pragma unroll
  for (int par = 0; par < 2; ++par){
    const int k = par * 32 + klA;
    const int r = dR[k], c = dC[k];
#pragma unroll
    for (int o = 0; o < 3; ++o){
      const int v = o - 1;                          // mean over o is order-free
      poff[par][o] = ((((r - v) & 15) << 4) | ((c - v) & 15)) << 8;
    }
  }
  const float* xb = x + (((long)b) << 21) + t0 + tA;
  char* const gwr = lds + LDS_G + ((klA >> 3) << 8) + (tA << 4) + ((klA & 7) << 1);
  char* const grd = lds + LDS_G + (q << 8) + (lr << 4);

  // phase-1 B pointers (direct global bf16x8 fragment loads; W1 is L2-resident)
  const char* bp1[4];
  float b1c[4];
#pragma unroll
  for (int ct = 0; ct < 4; ++ct){
    const int col = (w << 6) + (ct << 4) + lr;
    bp1[ct] = (const char*)w1b + col * 4096 + (q << 4);
    b1c[ct] = b1v[col];
  }

  f32x4 acc[3][4];
#pragma unroll
  for (int o = 0; o < 3; ++o)
#pragma unroll
    for (int ct = 0; ct < 4; ++ct)
      acc[o][ct] = f32x4{0.f, 0.f, 0.f, 0.f};

  // ---------------- prologue: stage gather tile 0, load B frags 0 ----------------
  {
    float g0[3];
#pragma unroll
    for (int o = 0; o < 3; ++o) g0[o] = xb[poff[0][o]];
#pragma unroll
    for (int o = 0; o < 3; ++o) *(unsigned short*)(gwr + (o << 10)) = f2bf(g0[o]);
  }
  bf16x8 bcur[4], bnxt[4];
#pragma unroll
  for (int ct = 0; ct < 4; ++ct) bcur[ct] = *(const bf16x8*)(bp1[ct]);
  __syncthreads();

  // ================= Phase 1: A1 = leaky(X @ W1^T + b1), K = 2048, 64 steps =====
#pragma unroll 1
  for (int it = 0; it < 32; ++it){
    const int i0 = it << 1;
    float gn[3];
    // ---- body A: compute step i0 (buf0), prefetch step i0+1 (buf1, par=1)
    {
      const float* xf = xb + ((long)it << 16);             // f = (i0+1)>>1 = it
#pragma unroll
      for (int o = 0; o < 3; ++o) gn[o] = xf[poff[1][o]];
#pragma unroll
      for (int ct = 0; ct < 4; ++ct)
        bnxt[ct] = *(const bf16x8*)(bp1[ct] + ((i0 + 1) << 6));
    }
    {
      bf16x8 af[3];
#pragma unroll
      for (int o = 0; o < 3; ++o) af[o] = *(const bf16x8*)(grd + (o << 10));
#pragma unroll
      for (int ct = 0; ct < 4; ++ct)
#pragma unroll
        for (int o = 0; o < 3; ++o)
          acc[o][ct] = __builtin_amdgcn_mfma_f32_16x16x32_bf16(af[o], bcur[ct], acc[o][ct], 0, 0, 0);
    }
#pragma unroll
    for (int o = 0; o < 3; ++o) *(unsigned short*)(gwr + 3072 + (o << 10)) = f2bf(gn[o]);
    __syncthreads();

    // ---- body B: compute step i0+1 (buf1), prefetch step i0+2 (buf0, par=0)
    if (it < 31){
      const float* xf = xb + (((long)it + 1) << 16);       // f = (i0+2)>>1 = it+1
#pragma unroll
      for (int o = 0; o < 3; ++o) gn[o] = xf[poff[0][o]];
#pragma unroll
      for (int ct = 0; ct < 4; ++ct)
        bcur[ct] = *(const bf16x8*)(bp1[ct] + ((i0 + 2) << 6));
    }
    {
      bf16x8 af[3];
#pragma unroll
      for (int o = 0; o < 3; ++o) af[o] = *(const bf16x8*)(grd + 3072 + (o << 10));
#pragma unroll
      for (int ct = 0; ct < 4; ++ct)
#pragma unroll
        for (int o = 0; o < 3; ++o)
          acc[o][ct] = __builtin_amdgcn_mfma_f32_16x16x32_bf16(af[o], bnxt[ct], acc[o][ct], 0, 0, 0);
    }
    if (it < 31){
#pragma unroll
      for (int o = 0; o < 3; ++o) *(unsigned short*)(gwr + (o << 10)) = f2bf(gn[o]);
    }
    __syncthreads();
  }

  // ---------------- epilogue 1: bias + leaky -> A1 bf16 in LDS (XOR-swizzled) ----
#pragma unroll
  for (int ct = 0; ct < 4; ++ct){
    const int col = (w << 6) + (ct << 4) + lr;
#pragma unroll
    for (int o = 0; o < 3; ++o)
#pragma unroll
      for (int r = 0; r < 4; ++r){
        float vv = acc[o][ct][r] + b1c[ct];
        vv = vv > 0.f ? vv : 0.01f * vv;
        const int trow = (q << 2) + r;               // D row = 4*(lane>>4)+reg
        int byt = (((o << 4) + trow) << 10) + (col << 1);
        byt ^= (trow & 7) << 4;
        *(unsigned short*)(lds + byt) = f2bf(vv);
      }
  }
  __syncthreads();

  // ================= Phase 2: out = mean_o leaky(A1 @ W2^T + b2), K=512, 16 steps
  const char* bp2[4];
  float b2c[4];
#pragma unroll
  for (int ct = 0; ct < 4; ++ct){
    const int col = (w << 6) + (ct << 4) + lr;
    bp2[ct] = (const char*)w2b + col * 1024 + (q << 4);
    b2c[ct] = b2v[col];
  }
  f32x4 acc2[3][4];
#pragma unroll
  for (int o = 0; o < 3; ++o)
#pragma unroll
    for (int ct = 0; ct < 4; ++ct)
      acc2[o][ct] = f32x4{0.f, 0.f, 0.f, 0.f};

  bf16x8 c0[4], c1[4];
#pragma unroll
  for (int ct = 0; ct < 4; ++ct) c0[ct] = *(const bf16x8*)(bp2[ct]);

#pragma unroll 1
  for (int it2 = 0; it2 < 8; ++it2){
    const int s0 = it2 << 1;
    // body A: step s0 with c0, prefetch s0+1 -> c1
#pragma unroll
    for (int ct = 0; ct < 4; ++ct) c1[ct] = *(const bf16x8*)(bp2[ct] + ((s0 + 1) << 6));
    {
      bf16x8 a2[3];
#pragma unroll
      for (int o = 0; o < 3; ++o){
        int byt = (((o << 4) + lr) << 10) + (((s0 << 5) + (q << 3)) << 1);
        byt ^= (lr & 7) << 4;
        a2[o] = *(const bf16x8*)(lds + byt);
      }
#pragma unroll
      for (int ct = 0; ct < 4; ++ct)
#pragma unroll
        for (int o = 0; o < 3; ++o)
          acc2[o][ct] = __builtin_amdgcn_mfma_f32_16x16x32_bf16(a2[o], c0[ct], acc2[o][ct], 0, 0, 0);
    }
    // body B: step s0+1 with c1, prefetch s0+2 -> c0
    if (it2 < 7){
#pragma unroll
      for (int ct = 0; ct < 4; ++ct) c0[ct] = *(const bf16x8*)(bp2[ct] + ((s0 + 2) << 6));
    }
    {
      bf16x8 a2[3];
#pragma unroll
      for (int o = 0; o < 3; ++o){
        int byt = (((o << 4) + lr) << 10) + ((((s0 + 1) << 5) + (q << 3)) << 1);
        byt ^= (lr & 7) << 4;
        a2[o] = *(const bf16x8*)(lds + byt);
      }
#pragma unroll
      for (int ct = 0; ct < 4; ++ct)
#pragma unroll
        for (int o = 0; o < 3; ++o)
          acc2[o][ct] = __builtin_amdgcn_mfma_f32_16x16x32_bf16(a2[o], c1[ct], acc2[o][ct], 0, 0, 0);
    }
  }

  // ---------------- epilogue 2: bias + leaky + mean(o) -> [B,H,T] store ----------
#pragma unroll
  for (int ct = 0; ct < 4; ++ct){
    const int col = (w << 6) + (ct << 4) + lr;
    f32x4 ov;
#pragma unroll
    for (int r = 0; r < 4; ++r){
      float s = 0.f;
#pragma unroll
      for (int o = 0; o < 3; ++o){
        float vv = acc2[o][ct][r] + b2c[ct];
        vv = vv > 0.f ? vv : 0.01f * vv;
        s += vv;
      }
      ov[r] = s * (1.f / 3.f);
    }
    *(f32x4*)(out + ((((long)b << 9) + col) << 8) + t0 + (q << 2)) = ov;
  }
}

extern "C" void kernel_launch(void* const* d_in, const int* in_sizes, int n_in,
                              void* d_out, int out_size, void* d_ws, size_t ws_size,
                              hipStream_t stream){
  const float* x  = (const float*)d_in[0];
  const float* w1 = (const float*)d_in[1];
  const float* b1 = (const float*)d_in[2];
  const float* w2 = (const float*)d_in[3];
  const float* b2 = (const float*)d_in[4];
  unsigned short* w1b = (unsigned short*)d_ws;            // 512*2048 bf16 = 2 MiB
  unsigned short* w2b = w1b + 512 * 2048;                 // 512*512  bf16 = 0.5 MiB
  conv_w_kernel<<<1280, 256, 0, stream>>>(w1, w2, w1b, w2b);
  fused_kernel<<<512, 512, 0, stream>>>(x, b1, b2, w1b, w2b, (float*)d_out);
}